// Round 1
// baseline (2681.048 us; speedup 1.0000x reference)
//
#include <hip/hip_runtime.h>

#define N_NODES 50000
#define E_TOTAL 800000
#define IN      128
#define HID     128
#define KE      259       // 2*IN + 1 + EDGE_F
#define EPB     32        // edges per block
#define NPB     8         // nodes per block
#define XOFF    ((size_t)N_NODES * HID)

__device__ __forceinline__ float silu_f(float x) {
    return x / (1.0f + __expf(-x));
}

__device__ __forceinline__ void f4arr(float4 v, float* a) {
    a[0] = v.x; a[1] = v.y; a[2] = v.z; a[3] = v.w;
}

// ---------------------------------------------------------------------------
// Edge kernel: 256 threads, EPB=32 edges/block.
// Thread t: tc = t&31 -> channels c0=tc*4..+3 ; te = t>>5 -> edges e0=te*4..+3
// 3 GEMMs (eW1 K=259, eW2 K=128, cW1 K=128) + cW2 dot + atomic scatter.
// ---------------------------------------------------------------------------
__global__ __launch_bounds__(256) void edge_kernel(
    const float* __restrict__ node_feat, const float* __restrict__ coord,
    const float* __restrict__ edge_feat,
    const int* __restrict__ src, const int* __restrict__ dst,
    const float* __restrict__ eW1, const float* __restrict__ eb1,
    const float* __restrict__ eW2, const float* __restrict__ eb2,
    const float* __restrict__ cW1, const float* __restrict__ cb1,
    const float* __restrict__ cW2,
    float* __restrict__ hacc,   // d_out h region  [N,128]
    float* __restrict__ xacc,   // d_out x region  [N,3]
    float* __restrict__ deg)    // d_ws            [N]
{
    __shared__ __attribute__((aligned(16))) float fbuf[EPB][260];   // f = [h_src|h_dst|radial|ef]
    __shared__ __attribute__((aligned(16))) float h1buf[EPB][132];
    __shared__ __attribute__((aligned(16))) float msgbuf[EPB][132];
    __shared__ int   sbuf[EPB], dbuf[EPB];
    __shared__ float xdbuf[EPB][4];

    const int t  = threadIdx.x;
    const int tc = t & 31;
    const int c0 = tc << 2;
    const int te = t >> 5;
    const int e0 = te << 2;
    const int e_base = blockIdx.x * EPB;

    // ---- phase A: edge indices ----
    if (t < EPB) {
        sbuf[t] = src[e_base + t];
        dbuf[t] = dst[e_base + t];
    }
    __syncthreads();

    // ---- phase B: gather features into LDS ----
    {
        const int c4 = (t & 31) << 2;
        const int eg = t >> 5;
#pragma unroll
        for (int r = 0; r < 4; ++r) {
            int e = eg + (r << 3);
            float4 hs = *reinterpret_cast<const float4*>(&node_feat[(size_t)sbuf[e] * IN + c4]);
            float4 hd = *reinterpret_cast<const float4*>(&node_feat[(size_t)dbuf[e] * IN + c4]);
            *reinterpret_cast<float4*>(&fbuf[e][c4])      = hs;
            *reinterpret_cast<float4*>(&fbuf[e][IN + c4]) = hd;
        }
    }
    if (t < EPB) {
        int e = t;
        int s = sbuf[e], d = dbuf[e];
        float dx = coord[(size_t)s*3+0] - coord[(size_t)d*3+0];
        float dy = coord[(size_t)s*3+1] - coord[(size_t)d*3+1];
        float dz = coord[(size_t)s*3+2] - coord[(size_t)d*3+2];
        float radial = dx*dx + dy*dy + dz*dz;
        float inv = 1.0f / (sqrtf(radial) + 1e-30f);
        fbuf[e][256] = radial;
        fbuf[e][257] = edge_feat[(size_t)(e_base + e)*2 + 0];
        fbuf[e][258] = edge_feat[(size_t)(e_base + e)*2 + 1];
        xdbuf[e][0] = dx * inv;
        xdbuf[e][1] = dy * inv;
        xdbuf[e][2] = dz * inv;
    }
    __syncthreads();

    // ---- GEMM1: f[32x259] @ eW1[259x128] -> silu -> h1 ----
    float acc[4][4];
#pragma unroll
    for (int j = 0; j < 4; ++j)
#pragma unroll
        for (int i = 0; i < 4; ++i) acc[j][i] = 0.0f;

    const float4* wv1 = reinterpret_cast<const float4*>(eW1);
    for (int kq = 0; kq < 64; ++kq) {
        int k = kq << 2;
        float f[4][4];
#pragma unroll
        for (int j = 0; j < 4; ++j) {
            float4 v = *reinterpret_cast<const float4*>(&fbuf[e0 + j][k]);
            f4arr(v, f[j]);
        }
#pragma unroll
        for (int kk = 0; kk < 4; ++kk) {
            float4 w = wv1[(size_t)(k + kk) * 32 + tc];
            float wa[4]; f4arr(w, wa);
#pragma unroll
            for (int j = 0; j < 4; ++j)
#pragma unroll
                for (int i = 0; i < 4; ++i)
                    acc[j][i] = fmaf(f[j][kk], wa[i], acc[j][i]);
        }
    }
    // tail k = 256..258
#pragma unroll
    for (int k = 256; k < 259; ++k) {
        float4 w = wv1[(size_t)k * 32 + tc];
        float wa[4]; f4arr(w, wa);
#pragma unroll
        for (int j = 0; j < 4; ++j) {
            float fe = fbuf[e0 + j][k];
#pragma unroll
            for (int i = 0; i < 4; ++i)
                acc[j][i] = fmaf(fe, wa[i], acc[j][i]);
        }
    }
    {
        float4 b = reinterpret_cast<const float4*>(eb1)[tc];
        float ba[4]; f4arr(b, ba);
#pragma unroll
        for (int j = 0; j < 4; ++j) {
            float4 o;
            o.x = silu_f(acc[j][0] + ba[0]);
            o.y = silu_f(acc[j][1] + ba[1]);
            o.z = silu_f(acc[j][2] + ba[2]);
            o.w = silu_f(acc[j][3] + ba[3]);
            *reinterpret_cast<float4*>(&h1buf[e0 + j][c0]) = o;
        }
    }
    __syncthreads();

    // ---- GEMM2: h1 @ eW2 -> silu -> msg ----
    float msg[4][4];
#pragma unroll
    for (int j = 0; j < 4; ++j)
#pragma unroll
        for (int i = 0; i < 4; ++i) msg[j][i] = 0.0f;

    const float4* wv2 = reinterpret_cast<const float4*>(eW2);
    for (int kq = 0; kq < 32; ++kq) {
        int k = kq << 2;
        float f[4][4];
#pragma unroll
        for (int j = 0; j < 4; ++j) {
            float4 v = *reinterpret_cast<const float4*>(&h1buf[e0 + j][k]);
            f4arr(v, f[j]);
        }
#pragma unroll
        for (int kk = 0; kk < 4; ++kk) {
            float4 w = wv2[(size_t)(k + kk) * 32 + tc];
            float wa[4]; f4arr(w, wa);
#pragma unroll
            for (int j = 0; j < 4; ++j)
#pragma unroll
                for (int i = 0; i < 4; ++i)
                    msg[j][i] = fmaf(f[j][kk], wa[i], msg[j][i]);
        }
    }
    {
        float4 b = reinterpret_cast<const float4*>(eb2)[tc];
        float ba[4]; f4arr(b, ba);
#pragma unroll
        for (int j = 0; j < 4; ++j) {
            float4 o;
            msg[j][0] = silu_f(msg[j][0] + ba[0]);
            msg[j][1] = silu_f(msg[j][1] + ba[1]);
            msg[j][2] = silu_f(msg[j][2] + ba[2]);
            msg[j][3] = silu_f(msg[j][3] + ba[3]);
            o.x = msg[j][0]; o.y = msg[j][1]; o.z = msg[j][2]; o.w = msg[j][3];
            *reinterpret_cast<float4*>(&msgbuf[e0 + j][c0]) = o;
        }
    }
    __syncthreads();

    // ---- GEMM3: msg @ cW1 -> silu -> t3 ; s = t3 . cW2 ----
    float acc3[4][4];
#pragma unroll
    for (int j = 0; j < 4; ++j)
#pragma unroll
        for (int i = 0; i < 4; ++i) acc3[j][i] = 0.0f;

    const float4* wv3 = reinterpret_cast<const float4*>(cW1);
    for (int kq = 0; kq < 32; ++kq) {
        int k = kq << 2;
        float f[4][4];
#pragma unroll
        for (int j = 0; j < 4; ++j) {
            float4 v = *reinterpret_cast<const float4*>(&msgbuf[e0 + j][k]);
            f4arr(v, f[j]);
        }
#pragma unroll
        for (int kk = 0; kk < 4; ++kk) {
            float4 w = wv3[(size_t)(k + kk) * 32 + tc];
            float wa[4]; f4arr(w, wa);
#pragma unroll
            for (int j = 0; j < 4; ++j)
#pragma unroll
                for (int i = 0; i < 4; ++i)
                    acc3[j][i] = fmaf(f[j][kk], wa[i], acc3[j][i]);
        }
    }
    float p[4];
    {
        float4 b = reinterpret_cast<const float4*>(cb1)[tc];
        float ba[4]; f4arr(b, ba);
        float4 cw = reinterpret_cast<const float4*>(cW2)[tc];
        float ca[4]; f4arr(cw, ca);
#pragma unroll
        for (int j = 0; j < 4; ++j) {
            p[j] = 0.0f;
#pragma unroll
            for (int i = 0; i < 4; ++i)
                p[j] += silu_f(acc3[j][i] + ba[i]) * ca[i];
        }
    }
    // butterfly over the 32 tc-lanes (same half-wave)
#pragma unroll
    for (int m = 1; m < 32; m <<= 1) {
#pragma unroll
        for (int j = 0; j < 4; ++j)
            p[j] += __shfl_xor(p[j], m);
    }

    // ---- scatter ----
#pragma unroll
    for (int j = 0; j < 4; ++j) {
        int gd = dbuf[e0 + j];
        float* dh = hacc + (size_t)gd * HID + c0;
#pragma unroll
        for (int i = 0; i < 4; ++i)
            atomicAdd(&dh[i], msg[j][i]);
    }
    if (tc == 0) {
#pragma unroll
        for (int j = 0; j < 4; ++j) {
            int e = e0 + j;
            int gd = dbuf[e];
            float s = p[j];
            atomicAdd(&xacc[(size_t)gd*3 + 0], s * xdbuf[e][0]);
            atomicAdd(&xacc[(size_t)gd*3 + 1], s * xdbuf[e][1]);
            atomicAdd(&xacc[(size_t)gd*3 + 2], s * xdbuf[e][2]);
            atomicAdd(&deg[gd], 1.0f);
        }
    }
}

// ---------------------------------------------------------------------------
// Node kernel: 256 threads, NPB=8 nodes/block. In-place update of d_out.
// ---------------------------------------------------------------------------
__global__ __launch_bounds__(256) void node_kernel(
    const float* __restrict__ node_feat, const float* __restrict__ coord,
    const float* __restrict__ nW1, const float* __restrict__ nb1,
    const float* __restrict__ nW2, const float* __restrict__ nb2,
    float* __restrict__ dout,          // full output buffer
    const float* __restrict__ deg)
{
    __shared__ __attribute__((aligned(16))) float catbuf[NPB][260];
    __shared__ __attribute__((aligned(16))) float h1buf[NPB][132];

    const int t  = threadIdx.x;
    const int tc = t & 31;
    const int c0 = tc << 2;
    const int te = t >> 5;          // node within block, 0..7
    const int nb = blockIdx.x * NPB;

    // stage concat = [node_feat | h_neigh]
#pragma unroll
    for (int r = 0; r < 2; ++r) {
        int q  = t + (r << 8);        // 0..511
        int nd = q >> 6;              // 0..7
        int k4 = (q & 63) << 2;       // 0..252
        int gn = nb + nd;
        float4 v;
        if (k4 < 128)
            v = *reinterpret_cast<const float4*>(&node_feat[(size_t)gn * IN + k4]);
        else
            v = *reinterpret_cast<const float4*>(&dout[(size_t)gn * HID + (k4 - 128)]);
        *reinterpret_cast<float4*>(&catbuf[nd][k4]) = v;
    }
    __syncthreads();

    // GEMM1: K=256
    float acc[4] = {0.f, 0.f, 0.f, 0.f};
    const float4* wv1 = reinterpret_cast<const float4*>(nW1);
    for (int kq = 0; kq < 64; ++kq) {
        int k = kq << 2;
        float4 fv = *reinterpret_cast<const float4*>(&catbuf[te][k]);
        float fa[4]; f4arr(fv, fa);
#pragma unroll
        for (int kk = 0; kk < 4; ++kk) {
            float4 w = wv1[(size_t)(k + kk) * 32 + tc];
            float wa[4]; f4arr(w, wa);
#pragma unroll
            for (int i = 0; i < 4; ++i)
                acc[i] = fmaf(fa[kk], wa[i], acc[i]);
        }
    }
    {
        float4 b = reinterpret_cast<const float4*>(nb1)[tc];
        float ba[4]; f4arr(b, ba);
        float4 o;
        o.x = silu_f(acc[0] + ba[0]);
        o.y = silu_f(acc[1] + ba[1]);
        o.z = silu_f(acc[2] + ba[2]);
        o.w = silu_f(acc[3] + ba[3]);
        *reinterpret_cast<float4*>(&h1buf[te][c0]) = o;
    }
    __syncthreads();

    // GEMM2: K=128, no activation
    float acc2[4] = {0.f, 0.f, 0.f, 0.f};
    const float4* wv2 = reinterpret_cast<const float4*>(nW2);
    for (int kq = 0; kq < 32; ++kq) {
        int k = kq << 2;
        float4 fv = *reinterpret_cast<const float4*>(&h1buf[te][k]);
        float fa[4]; f4arr(fv, fa);
#pragma unroll
        for (int kk = 0; kk < 4; ++kk) {
            float4 w = wv2[(size_t)(k + kk) * 32 + tc];
            float wa[4]; f4arr(w, wa);
#pragma unroll
            for (int i = 0; i < 4; ++i)
                acc2[i] = fmaf(fa[kk], wa[i], acc2[i]);
        }
    }
    {
        float4 b = reinterpret_cast<const float4*>(nb2)[tc];
        float ba[4]; f4arr(b, ba);
        int gn = nb + te;
        float4 o;
        o.x = acc2[0] + ba[0];
        o.y = acc2[1] + ba[1];
        o.z = acc2[2] + ba[2];
        o.w = acc2[3] + ba[3];
        *reinterpret_cast<float4*>(&dout[(size_t)gn * HID + c0]) = o;
    }

    // x update
    if (t < NPB * 3) {
        int nd = t / 3, d = t - 3 * nd;
        int gn = nb + nd;
        size_t xi = XOFF + (size_t)gn * 3 + d;
        float dg = deg[gn];
        dg = dg > 1.0f ? dg : 1.0f;
        dout[xi] = coord[(size_t)gn * 3 + d] + dout[xi] / dg;
    }
}

extern "C" void kernel_launch(void* const* d_in, const int* in_sizes, int n_in,
                              void* d_out, int out_size, void* d_ws, size_t ws_size,
                              hipStream_t stream) {
    const float* node_feat = (const float*)d_in[0];
    const float* coord     = (const float*)d_in[1];
    const float* edge_feat = (const float*)d_in[2];
    const int*   src       = (const int*)d_in[3];
    const int*   dst       = (const int*)d_in[4];
    const float* eW1 = (const float*)d_in[5];
    const float* eb1 = (const float*)d_in[6];
    const float* eW2 = (const float*)d_in[7];
    const float* eb2 = (const float*)d_in[8];
    const float* nW1 = (const float*)d_in[9];
    const float* nb1 = (const float*)d_in[10];
    const float* nW2 = (const float*)d_in[11];
    const float* nb2 = (const float*)d_in[12];
    const float* cW1 = (const float*)d_in[13];
    const float* cb1 = (const float*)d_in[14];
    const float* cW2 = (const float*)d_in[15];

    float* out = (float*)d_out;
    float* deg = (float*)d_ws;

    // zero accumulators (h region, x region) and degree counters
    hipMemsetAsync(d_out, 0, (size_t)out_size * sizeof(float), stream);
    hipMemsetAsync(d_ws, 0, (size_t)N_NODES * sizeof(float), stream);

    edge_kernel<<<E_TOTAL / EPB, 256, 0, stream>>>(
        node_feat, coord, edge_feat, src, dst,
        eW1, eb1, eW2, eb2, cW1, cb1, cW2,
        out, out + XOFF, deg);

    node_kernel<<<N_NODES / NPB, 256, 0, stream>>>(
        node_feat, coord, nW1, nb1, nW2, nb2, out, deg);
}

// Round 2
// 794.565 us; speedup vs baseline: 3.3742x; 3.3742x over previous
//
#include <hip/hip_runtime.h>

#define N_NODES 50000
#define E_TOTAL 800000
#define IN      128
#define HID     128
#define EPB     32        // edges per block
#define NPB     8         // nodes per block
#define XOFF    ((size_t)N_NODES * HID)
#define FP      296       // fbuf pitch (ushorts) : 288 K-pad + 8 bank pad
#define HP      136       // h1buf pitch (ushorts)

typedef __attribute__((ext_vector_type(8))) short short8v;
typedef __attribute__((ext_vector_type(4))) float f32x4;

__device__ __forceinline__ float silu_f(float x) {
    return x / (1.0f + __expf(-x));
}

__device__ __forceinline__ ushort f2bf(float x) {
    uint u = __float_as_uint(x);
    u += 0x7fff + ((u >> 16) & 1);     // RNE
    return (ushort)(u >> 16);
}

__device__ __forceinline__ void f4arr(float4 v, float* a) {
    a[0] = v.x; a[1] = v.y; a[2] = v.z; a[3] = v.w;
}

// ---------------------------------------------------------------------------
// Weight repack: f32 [K][128] -> bf16 MFMA fragment order.
// Entry (kt, n, l) holds 8 bf16: W[kt*32 + 8*(l>>4) + j][n*16 + (l&15)], j=0..7
// (same k-mapping used for A fragments -> any in-slot k permutation cancels).
// pk1: eW1 padded K 259->288 (9 kt). pk2: eW2 (4 kt). pk3: cW1 (4 kt).
// ---------------------------------------------------------------------------
__global__ __launch_bounds__(256) void conv_weights(
    const float* __restrict__ eW1, const float* __restrict__ eW2,
    const float* __restrict__ cW1,
    ushort* __restrict__ pk1, ushort* __restrict__ pk2, ushort* __restrict__ pk3)
{
    int id = blockIdx.x * 256 + threadIdx.x;
    const float* W; ushort* dst_; int K, idx;
    if (id < 4608)       { idx = id;        W = eW1; dst_ = pk1; K = 259; }
    else if (id < 6656)  { idx = id - 4608; W = eW2; dst_ = pk2; K = 128; }
    else if (id < 8704)  { idx = id - 6656; W = cW1; dst_ = pk3; K = 128; }
    else return;
    int kt = idx >> 9;            // /(8*64)
    int n  = (idx >> 6) & 7;
    int l  = idx & 63;
    int col = (n << 4) + (l & 15);
    short8v o;
#pragma unroll
    for (int j = 0; j < 8; ++j) {
        int k = (kt << 5) + ((l >> 4) << 3) + j;
        float v = (k < K) ? W[(size_t)k * 128 + col] : 0.0f;
        o[j] = (short)f2bf(v);
    }
    *reinterpret_cast<short8v*>(dst_ + (size_t)idx * 8) = o;
}

// ---------------------------------------------------------------------------
// Edge kernel (MFMA): 256 thr = 4 waves, EPB=32 edges/block.
// Wave w: eh=w>>1 -> edge rows 16*eh..+15 ; ch=w&1 -> cols 64*ch..+63.
// GEMM1 K=288(pad), GEMM2 K=128, GEMM3 K=128, cW2 dot via shfl reduce.
// ---------------------------------------------------------------------------
__global__ __launch_bounds__(256, 4) void edge_kernel(
    const float* __restrict__ node_feat, const float* __restrict__ coord,
    const float* __restrict__ edge_feat,
    const int* __restrict__ src, const int* __restrict__ dst,
    const ushort* __restrict__ pk1, const ushort* __restrict__ pk2,
    const ushort* __restrict__ pk3,
    const float* __restrict__ eb1, const float* __restrict__ eb2,
    const float* __restrict__ cb1, const float* __restrict__ cW2,
    float* __restrict__ hacc, float* __restrict__ xacc, float* __restrict__ deg)
{
    __shared__ __attribute__((aligned(16))) ushort fbuf[EPB][FP];   // reused as msgbuf
    __shared__ __attribute__((aligned(16))) ushort h1buf[EPB][HP];
    __shared__ int   sbuf[EPB], dbuf[EPB];
    __shared__ float xdbuf[EPB][4];
    __shared__ float pbuf[2][2][16];

    const int t   = threadIdx.x;
    const int l   = t & 63;
    const int w   = t >> 6;
    const int eh  = w >> 1;
    const int ch  = w & 1;
    const int r16 = l & 15;
    const int g   = l >> 4;
    const int e_base = blockIdx.x * EPB;

    if (t < EPB) { sbuf[t] = src[e_base + t]; dbuf[t] = dst[e_base + t]; }
    __syncthreads();

    // ---- gather: f = [h_src | h_dst | radial | ef] as bf16 into fbuf ----
    {
        const int c8  = (t & 31) << 3;     // 0..248
        const int te0 = t >> 5;
#pragma unroll
        for (int r = 0; r < 4; ++r) {
            int e = te0 + (r << 3);
            const float* base = (c8 < 128)
                ? node_feat + (size_t)sbuf[e] * IN + c8
                : node_feat + (size_t)dbuf[e] * IN + (c8 - 128);
            float4 v0 = *reinterpret_cast<const float4*>(base);
            float4 v1 = *reinterpret_cast<const float4*>(base + 4);
            short8v pk;
            pk[0] = (short)f2bf(v0.x); pk[1] = (short)f2bf(v0.y);
            pk[2] = (short)f2bf(v0.z); pk[3] = (short)f2bf(v0.w);
            pk[4] = (short)f2bf(v1.x); pk[5] = (short)f2bf(v1.y);
            pk[6] = (short)f2bf(v1.z); pk[7] = (short)f2bf(v1.w);
            *reinterpret_cast<short8v*>(&fbuf[e][c8]) = pk;
        }
    }
    if (t < EPB) {
        int e = t, s = sbuf[e], d = dbuf[e];
        float dx = coord[(size_t)s*3+0] - coord[(size_t)d*3+0];
        float dy = coord[(size_t)s*3+1] - coord[(size_t)d*3+1];
        float dz = coord[(size_t)s*3+2] - coord[(size_t)d*3+2];
        float radial = dx*dx + dy*dy + dz*dz;
        float inv = 1.0f / (sqrtf(radial) + 1e-30f);
        fbuf[e][256] = f2bf(radial);
        fbuf[e][257] = f2bf(edge_feat[(size_t)(e_base + e)*2 + 0]);
        fbuf[e][258] = f2bf(edge_feat[(size_t)(e_base + e)*2 + 1]);
#pragma unroll
        for (int k = 259; k < 288; ++k) fbuf[e][k] = 0;
        xdbuf[e][0] = dx * inv; xdbuf[e][1] = dy * inv; xdbuf[e][2] = dz * inv;
    }
    __syncthreads();

    const f32x4 zero = {0.0f, 0.0f, 0.0f, 0.0f};
    const short8v* pkv1 = reinterpret_cast<const short8v*>(pk1);
    const short8v* pkv2 = reinterpret_cast<const short8v*>(pk2);
    const short8v* pkv3 = reinterpret_cast<const short8v*>(pk3);

    // ---- GEMM1: f[32x288] @ eW1b -> silu -> h1 (bf16 LDS) ----
    f32x4 acc[4];
#pragma unroll
    for (int nt = 0; nt < 4; ++nt) acc[nt] = zero;
    for (int kt = 0; kt < 9; ++kt) {
        short8v a = *reinterpret_cast<const short8v*>(&fbuf[(eh<<4) + r16][(kt<<5) + (g<<3)]);
#pragma unroll
        for (int nt = 0; nt < 4; ++nt) {
            short8v b = pkv1[(size_t)(((kt<<3) + (ch<<2) + nt) << 6) + l];
            acc[nt] = __builtin_amdgcn_mfma_f32_16x16x32_bf16(a, b, acc[nt], 0, 0, 0);
        }
    }
#pragma unroll
    for (int nt = 0; nt < 4; ++nt) {
        int col = (ch << 6) + (nt << 4) + r16;
        float bb = eb1[col];
#pragma unroll
        for (int r = 0; r < 4; ++r)
            h1buf[(eh<<4) + (g<<2) + r][col] = f2bf(silu_f(acc[nt][r] + bb));
    }
    __syncthreads();

    // ---- GEMM2: h1 @ eW2b -> silu -> msg (f32 regs + bf16 into fbuf) ----
#pragma unroll
    for (int nt = 0; nt < 4; ++nt) acc[nt] = zero;
    for (int kt = 0; kt < 4; ++kt) {
        short8v a = *reinterpret_cast<const short8v*>(&h1buf[(eh<<4) + r16][(kt<<5) + (g<<3)]);
#pragma unroll
        for (int nt = 0; nt < 4; ++nt) {
            short8v b = pkv2[(size_t)(((kt<<3) + (ch<<2) + nt) << 6) + l];
            acc[nt] = __builtin_amdgcn_mfma_f32_16x16x32_bf16(a, b, acc[nt], 0, 0, 0);
        }
    }
    float msg[4][4];
#pragma unroll
    for (int nt = 0; nt < 4; ++nt) {
        int col = (ch << 6) + (nt << 4) + r16;
        float bb = eb2[col];
#pragma unroll
        for (int r = 0; r < 4; ++r) {
            float v = silu_f(acc[nt][r] + bb);
            msg[nt][r] = v;
            fbuf[(eh<<4) + (g<<2) + r][col] = f2bf(v);
        }
    }
    __syncthreads();

    // ---- scatter h (fire-and-forget, overlaps GEMM3) ----
#pragma unroll
    for (int nt = 0; nt < 4; ++nt) {
        int col = (ch << 6) + (nt << 4) + r16;
#pragma unroll
        for (int r = 0; r < 4; ++r) {
            int gd = dbuf[(eh<<4) + (g<<2) + r];
            atomicAdd(&hacc[(size_t)gd * HID + col], msg[nt][r]);
        }
    }

    // ---- GEMM3: msg @ cW1b -> silu -> dot cW2 ----
#pragma unroll
    for (int nt = 0; nt < 4; ++nt) acc[nt] = zero;
    for (int kt = 0; kt < 4; ++kt) {
        short8v a = *reinterpret_cast<const short8v*>(&fbuf[(eh<<4) + r16][(kt<<5) + (g<<3)]);
#pragma unroll
        for (int nt = 0; nt < 4; ++nt) {
            short8v b = pkv3[(size_t)(((kt<<3) + (ch<<2) + nt) << 6) + l];
            acc[nt] = __builtin_amdgcn_mfma_f32_16x16x32_bf16(a, b, acc[nt], 0, 0, 0);
        }
    }
    float part[4] = {0.f, 0.f, 0.f, 0.f};
#pragma unroll
    for (int nt = 0; nt < 4; ++nt) {
        int col = (ch << 6) + (nt << 4) + r16;
        float bb = cb1[col];
        float cw = cW2[col];
#pragma unroll
        for (int r = 0; r < 4; ++r)
            part[r] += silu_f(acc[nt][r] + bb) * cw;
    }
#pragma unroll
    for (int m = 1; m < 16; m <<= 1)
#pragma unroll
        for (int r = 0; r < 4; ++r)
            part[r] += __shfl_xor(part[r], m);
    if (r16 == 0) {
#pragma unroll
        for (int r = 0; r < 4; ++r)
            pbuf[eh][ch][(g<<2) + r] = part[r];
    }
    __syncthreads();

    if (t < EPB) {
        int e = t;
        float s = pbuf[e >> 4][0][e & 15] + pbuf[e >> 4][1][e & 15];
        int gd = dbuf[e];
        atomicAdd(&xacc[(size_t)gd*3 + 0], s * xdbuf[e][0]);
        atomicAdd(&xacc[(size_t)gd*3 + 1], s * xdbuf[e][1]);
        atomicAdd(&xacc[(size_t)gd*3 + 2], s * xdbuf[e][2]);
        atomicAdd(&deg[gd], 1.0f);
    }
}

// ---------------------------------------------------------------------------
// Node kernel: 256 threads, NPB=8 nodes/block. In-place update of d_out. f32.
// ---------------------------------------------------------------------------
__global__ __launch_bounds__(256) void node_kernel(
    const float* __restrict__ node_feat, const float* __restrict__ coord,
    const float* __restrict__ nW1, const float* __restrict__ nb1,
    const float* __restrict__ nW2, const float* __restrict__ nb2,
    float* __restrict__ dout, const float* __restrict__ deg)
{
    __shared__ __attribute__((aligned(16))) float catbuf[NPB][260];
    __shared__ __attribute__((aligned(16))) float h1buf[NPB][132];

    const int t  = threadIdx.x;
    const int tc = t & 31;
    const int c0 = tc << 2;
    const int te = t >> 5;
    const int nb = blockIdx.x * NPB;

#pragma unroll
    for (int r = 0; r < 2; ++r) {
        int q  = t + (r << 8);
        int nd = q >> 6;
        int k4 = (q & 63) << 2;
        int gn = nb + nd;
        float4 v;
        if (k4 < 128)
            v = *reinterpret_cast<const float4*>(&node_feat[(size_t)gn * IN + k4]);
        else
            v = *reinterpret_cast<const float4*>(&dout[(size_t)gn * HID + (k4 - 128)]);
        *reinterpret_cast<float4*>(&catbuf[nd][k4]) = v;
    }
    __syncthreads();

    float acc[4] = {0.f, 0.f, 0.f, 0.f};
    const float4* wv1 = reinterpret_cast<const float4*>(nW1);
    for (int kq = 0; kq < 64; ++kq) {
        int k = kq << 2;
        float4 fv = *reinterpret_cast<const float4*>(&catbuf[te][k]);
        float fa[4]; f4arr(fv, fa);
#pragma unroll
        for (int kk = 0; kk < 4; ++kk) {
            float4 wv = wv1[(size_t)(k + kk) * 32 + tc];
            float wa[4]; f4arr(wv, wa);
#pragma unroll
            for (int i = 0; i < 4; ++i)
                acc[i] = fmaf(fa[kk], wa[i], acc[i]);
        }
    }
    {
        float4 b = reinterpret_cast<const float4*>(nb1)[tc];
        float ba[4]; f4arr(b, ba);
        float4 o;
        o.x = silu_f(acc[0] + ba[0]);
        o.y = silu_f(acc[1] + ba[1]);
        o.z = silu_f(acc[2] + ba[2]);
        o.w = silu_f(acc[3] + ba[3]);
        *reinterpret_cast<float4*>(&h1buf[te][c0]) = o;
    }
    __syncthreads();

    float acc2[4] = {0.f, 0.f, 0.f, 0.f};
    const float4* wv2 = reinterpret_cast<const float4*>(nW2);
    for (int kq = 0; kq < 32; ++kq) {
        int k = kq << 2;
        float4 fv = *reinterpret_cast<const float4*>(&h1buf[te][k]);
        float fa[4]; f4arr(fv, fa);
#pragma unroll
        for (int kk = 0; kk < 4; ++kk) {
            float4 wv = wv2[(size_t)(k + kk) * 32 + tc];
            float wa[4]; f4arr(wv, wa);
#pragma unroll
            for (int i = 0; i < 4; ++i)
                acc2[i] = fmaf(fa[kk], wa[i], acc2[i]);
        }
    }
    {
        float4 b = reinterpret_cast<const float4*>(nb2)[tc];
        float ba[4]; f4arr(b, ba);
        int gn = nb + te;
        float4 o;
        o.x = acc2[0] + ba[0];
        o.y = acc2[1] + ba[1];
        o.z = acc2[2] + ba[2];
        o.w = acc2[3] + ba[3];
        *reinterpret_cast<float4*>(&dout[(size_t)gn * HID + c0]) = o;
    }

    if (t < NPB * 3) {
        int nd = t / 3, d = t - 3 * nd;
        int gn = nb + nd;
        size_t xi = XOFF + (size_t)gn * 3 + d;
        float dg = deg[gn];
        dg = dg > 1.0f ? dg : 1.0f;
        dout[xi] = coord[(size_t)gn * 3 + d] + dout[xi] / dg;
    }
}

extern "C" void kernel_launch(void* const* d_in, const int* in_sizes, int n_in,
                              void* d_out, int out_size, void* d_ws, size_t ws_size,
                              hipStream_t stream) {
    const float* node_feat = (const float*)d_in[0];
    const float* coord     = (const float*)d_in[1];
    const float* edge_feat = (const float*)d_in[2];
    const int*   src       = (const int*)d_in[3];
    const int*   dst       = (const int*)d_in[4];
    const float* eW1 = (const float*)d_in[5];
    const float* eb1 = (const float*)d_in[6];
    const float* eW2 = (const float*)d_in[7];
    const float* eb2 = (const float*)d_in[8];
    const float* nW1 = (const float*)d_in[9];
    const float* nb1 = (const float*)d_in[10];
    const float* nW2 = (const float*)d_in[11];
    const float* nb2 = (const float*)d_in[12];
    const float* cW1 = (const float*)d_in[13];
    const float* cb1 = (const float*)d_in[14];
    const float* cW2 = (const float*)d_in[15];

    float* out = (float*)d_out;
    float* deg = (float*)d_ws;
    // ws layout: deg f32[50000] (200000 B) | pk1 bf16 288*128 | pk2 128*128 | pk3 128*128
    ushort* pkb = (ushort*)((char*)d_ws + 200000);
    ushort* pk1 = pkb;
    ushort* pk2 = pkb + 36864;
    ushort* pk3 = pkb + 36864 + 16384;

    hipMemsetAsync(d_out, 0, (size_t)out_size * sizeof(float), stream);
    hipMemsetAsync(d_ws, 0, (size_t)N_NODES * sizeof(float), stream);

    conv_weights<<<34, 256, 0, stream>>>(eW1, eW2, cW1, pk1, pk2, pk3);

    edge_kernel<<<E_TOTAL / EPB, 256, 0, stream>>>(
        node_feat, coord, edge_feat, src, dst,
        pk1, pk2, pk3, eb1, eb2, cb1, cW2,
        out, out + XOFF, deg);

    node_kernel<<<N_NODES / NPB, 256, 0, stream>>>(
        node_feat, coord, nW1, nb1, nW2, nb2, out, deg);
}